// Round 1
// baseline (154.610 us; speedup 1.0000x reference)
//
#include <hip/hip_runtime.h>
#include <math.h>

#define B   8
#define NA  33600
#define M   64
#define NC  80
#define KK  13
#define EPSF 1e-9f
#define PIF 3.14159265358979323846f

#define NPOS 2048
#define K1_THREADS 512

// ---------------------------------------------------------------- helpers

__device__ __forceinline__ float circle_iou(float gx, float gy, float gr,
                                            float px, float py, float pr) {
    float dx = gx - px, dy = gy - py;
    float d  = sqrtf(dx * dx + dy * dy + 1e-12f);
    float r0sq = gr * gr, r1sq = pr * pr;
    float d1 = (r0sq - r1sq + d * d) / (2.0f * d);
    float d2 = d - d1;
    float t0 = fminf(fmaxf(d1 / fmaxf(gr, EPSF), -1.0f), 1.0f);
    float t1 = fminf(fmaxf(d2 / fmaxf(pr, EPSF), -1.0f), 1.0f);
    float a0 = r0sq * acosf(t0) - d1 * sqrtf(fmaxf(r0sq - d1 * d1, 0.0f));
    float a1 = r1sq * acosf(t1) - d2 * sqrtf(fmaxf(r1sq - d2 * d2, 0.0f));
    float lens = a0 + a1;
    float rmin = fminf(gr, pr);
    float contained = PIF * rmin * rmin;
    float inter = (d >= gr + pr) ? 0.0f
                : ((d <= fabsf(gr - pr)) ? contained : lens);
    float uni = PIF * r0sq + PIF * r1sq - inter;
    return (uni > 0.0f) ? inter / uni : 0.0f;
}

// masked overlap + align_metric for one (b, gt, anchor)
__device__ __forceinline__ void ov_met(const float* __restrict__ pd_scores,
                                       const float* __restrict__ pd_circles,
                                       const float* __restrict__ anc,
                                       int b, int a,
                                       float gx, float gy, float gr, int gl, float gmask,
                                       float* ov_out, float* met_out) {
    float ax = anc[2 * a], ay = anc[2 * a + 1];
    float dx = ax - gx, dy = ay - gy;
    float dan = sqrtf(dx * dx + dy * dy);
    float ov = 0.0f, met = 0.0f;
    if (gmask > 0.0f && dan < gr) {
        int base = (b * NA + a) * 3;
        float px = pd_circles[base + 0];
        float py = pd_circles[base + 1];
        float pr = pd_circles[base + 2];
        float iou = circle_iou(gx, gy, gr, px, py, pr);
        ov = iou * gmask;                       // overlaps * mask_valid
        float sc = pd_scores[(size_t)(b * NA + a) * NC + gl] * gmask;
        float o2 = ov * ov;
        met = sc * (o2 * o2 * o2);              // score^1 * ov^6
    }
    *ov_out = ov; *met_out = met;
}

// ---------------------------------------------------------------- K0 init

__global__ void k_init(int* __restrict__ fg_count, int* __restrict__ sel_m,
                       int* __restrict__ pos_align_i, int* __restrict__ pos_ov_i) {
    int i = blockIdx.x * blockDim.x + threadIdx.x;
    if (i < B * NA) { fg_count[i] = 0; sel_m[i] = 0x7fffffff; }
    if (i < B * M)  { pos_align_i[i] = 0; pos_ov_i[i] = 0; }
}

// ---------------------------------------------------------------- K1 top-k per (b,m)

__global__ __launch_bounds__(K1_THREADS)
void k_topk(const float* __restrict__ pd_scores, const float* __restrict__ pd_circles,
            const float* __restrict__ anc, const int* __restrict__ gt_labels,
            const float* __restrict__ gt_circles, const float* __restrict__ mask_gt,
            int* __restrict__ topk_a) {
    int bm = blockIdx.x;
    int b  = bm / M;
    __shared__ int   s_cnt;
    __shared__ int   s_idx[NPOS];
    __shared__ float s_val[NPOS];
    __shared__ float r_val[K1_THREADS];
    __shared__ int   r_anc[K1_THREADS];
    __shared__ int   r_pos[K1_THREADS];
    __shared__ int   s_win[KK];
    int tid = threadIdx.x;

    float gmask = mask_gt[bm];
    if (!(gmask > 0.0f)) {
        // inactive gt: reference zeroes its topk via counts>1 -> contributes nothing
        if (tid < KK) topk_a[bm * KK + tid] = -1;
        return;
    }
    float gx = gt_circles[bm * 3 + 0];
    float gy = gt_circles[bm * 3 + 1];
    float gr = gt_circles[bm * 3 + 2];
    int gl = gt_labels[bm];
    gl = gl < 0 ? 0 : (gl > NC - 1 ? NC - 1 : gl);

    if (tid == 0) s_cnt = 0;
    __syncthreads();

    // phase A: compact positive-metric anchors
    for (int a = tid; a < NA; a += K1_THREADS) {
        float ov, met;
        ov_met(pd_scores, pd_circles, anc, b, a, gx, gy, gr, gl, gmask, &ov, &met);
        if (met > 0.0f) {
            int p = atomicAdd(&s_cnt, 1);
            if (p < NPOS) { s_idx[p] = a; s_val[p] = met; }
        }
    }
    __syncthreads();
    int cnt = s_cnt; if (cnt > NPOS) cnt = NPOS;

    // phase B: 13 rounds of argmax (val desc, anchor-index asc) == lax.top_k order
    for (int k = 0; k < KK; k++) {
        float bv = -1.0f; int ba = 0x7fffffff; int bp = -1;
        for (int i = tid; i < cnt; i += K1_THREADS) {
            float v = s_val[i]; int a = s_idx[i];
            if (v > bv || (v == bv && a < ba)) { bv = v; ba = a; bp = i; }
        }
        r_val[tid] = bv; r_anc[tid] = ba; r_pos[tid] = bp;
        __syncthreads();
        for (int s = K1_THREADS / 2; s > 0; s >>= 1) {
            if (tid < s) {
                float v2 = r_val[tid + s]; int a2 = r_anc[tid + s];
                if (v2 > r_val[tid] || (v2 == r_val[tid] && a2 < r_anc[tid])) {
                    r_val[tid] = v2; r_anc[tid] = a2; r_pos[tid] = r_pos[tid + s];
                }
            }
            __syncthreads();
        }
        if (tid == 0) {
            if (r_val[0] > 0.0f) { s_win[k] = r_anc[0]; s_val[r_pos[0]] = -1.0f; }
            else s_win[k] = -2;   // needs zero-fill
        }
        __syncthreads();
    }

    // zero-fill: top_k ties at 0 pick lowest anchor indices with metric == 0
    if (tid == 0) {
        int a = 0;
        for (int k = 0; k < KK; k++) {
            if (s_win[k] == -2) {
                s_win[k] = -1;
                while (a < NA) {
                    float ov, met;
                    ov_met(pd_scores, pd_circles, anc, b, a, gx, gy, gr, gl, gmask, &ov, &met);
                    int take = !(met > 0.0f);
                    if (take) { s_win[k] = a; a++; break; }
                    a++;
                }
            }
        }
    }
    __syncthreads();

    // phase C: a winner enters mask_pos only if its anchor center is inside the gt
    if (tid < KK) {
        int a = s_win[tid];
        int out = -1;
        if (a >= 0) {
            float ax = anc[2 * a], ay = anc[2 * a + 1];
            float dx = ax - gx, dy = ay - gy;
            if (sqrtf(dx * dx + dy * dy) < gr) out = a;
        }
        topk_a[bm * KK + tid] = out;
    }
}

// ---------------------------------------------------------------- K2 scatter

__global__ void k_scatter(const int* __restrict__ topk_a,
                          int* __restrict__ fg_count, int* __restrict__ sel_m) {
    int i = blockIdx.x * blockDim.x + threadIdx.x;
    if (i >= B * M * KK) return;
    int a = topk_a[i];
    if (a < 0) return;
    int bm = i / KK;
    int b = bm / M, m = bm % M;
    atomicAdd(&fg_count[b * NA + a], 1);
    atomicMin(&sel_m[b * NA + a], m);
}

// ---------------------------------------------------------------- K3 per-anchor resolve

__global__ void k_resolve(const float* __restrict__ pd_circles, const float* __restrict__ anc,
                          const int* __restrict__ gt_labels, const float* __restrict__ gt_circles,
                          const float* __restrict__ mask_gt,
                          const int* __restrict__ fg_count, const int* __restrict__ sel_m,
                          int* __restrict__ assigned,
                          float* __restrict__ out_labels, float* __restrict__ out_circles,
                          float* __restrict__ out_fg, float* __restrict__ out_gtidx) {
    int i = blockIdx.x * blockDim.x + threadIdx.x;
    if (i >= B * NA) return;
    int b = i / NA, a = i - b * NA;
    int c = fg_count[i];
    int g = 0, fg = 0;
    if (c == 1) { g = sel_m[i]; fg = 1; }
    else if (c > 1) {
        // jnp.argmax over masked overlaps, lowest index wins ties
        float ax = anc[2 * a], ay = anc[2 * a + 1];
        int pbase = i * 3;
        float px = pd_circles[pbase], py = pd_circles[pbase + 1], pr = pd_circles[pbase + 2];
        float best = -1.0f; int bmx = 0;
        for (int m = 0; m < M; m++) {
            float gmask = mask_gt[b * M + m];
            float gx = gt_circles[(b * M + m) * 3 + 0];
            float gy = gt_circles[(b * M + m) * 3 + 1];
            float grr = gt_circles[(b * M + m) * 3 + 2];
            float dx = ax - gx, dy = ay - gy;
            float ov = 0.0f;
            if (gmask > 0.0f && sqrtf(dx * dx + dy * dy) < grr)
                ov = circle_iou(gx, gy, grr, px, py, pr) * gmask;
            if (ov > best) { best = ov; bmx = m; }
        }
        g = bmx; fg = 1;
    }
    assigned[i] = fg ? g : -1;
    int lbl = gt_labels[b * M + g]; if (lbl < 0) lbl = 0;  // clip(.., 0, None)
    out_labels[i] = (float)lbl;
    out_circles[(size_t)i * 3 + 0] = gt_circles[(b * M + g) * 3 + 0];
    out_circles[(size_t)i * 3 + 1] = gt_circles[(b * M + g) * 3 + 1];
    out_circles[(size_t)i * 3 + 2] = gt_circles[(b * M + g) * 3 + 2];
    out_fg[i]    = fg ? 1.0f : 0.0f;
    out_gtidx[i] = (float)g;
}

// ---------------------------------------------------------------- K4 pos_align / pos_overlaps

__global__ void k_posmax(const float* __restrict__ pd_scores, const float* __restrict__ pd_circles,
                         const float* __restrict__ anc, const int* __restrict__ gt_labels,
                         const float* __restrict__ gt_circles, const float* __restrict__ mask_gt,
                         const int* __restrict__ assigned, float* __restrict__ am_val,
                         int* __restrict__ pos_align_i, int* __restrict__ pos_ov_i) {
    int i = blockIdx.x * blockDim.x + threadIdx.x;
    if (i >= B * NA) return;
    int g = assigned[i];
    if (g < 0) { am_val[i] = 0.0f; return; }
    int b = i / NA, a = i - b * NA;
    float gmask = mask_gt[b * M + g];
    float gx = gt_circles[(b * M + g) * 3 + 0];
    float gy = gt_circles[(b * M + g) * 3 + 1];
    float gr = gt_circles[(b * M + g) * 3 + 2];
    int gl = gt_labels[b * M + g];
    gl = gl < 0 ? 0 : (gl > NC - 1 ? NC - 1 : gl);
    float ov, met;
    ov_met(pd_scores, pd_circles, anc, b, a, gx, gy, gr, gl, gmask, &ov, &met);
    am_val[i] = met;
    // values >= 0: int-compare == float-compare
    atomicMax(&pos_align_i[b * M + g], __float_as_int(met));
    atomicMax(&pos_ov_i[b * M + g],    __float_as_int(ov));
}

// ---------------------------------------------------------------- K5 target_scores (86 MB write)

__global__ void k_scores(const int* __restrict__ assigned, const float* __restrict__ am_val,
                         const int* __restrict__ pos_align_i, const int* __restrict__ pos_ov_i,
                         const int* __restrict__ gt_labels,
                         float* __restrict__ out_scores) {
    int q = blockIdx.x * blockDim.x + threadIdx.x;      // one float4 per thread
    if (q >= (B * NA * NC) / 4) return;
    int idx = q * 4;
    int row = idx / NC;
    int c0  = idx - row * NC;
    float4 v = make_float4(0.f, 0.f, 0.f, 0.f);
    int g = assigned[row];
    if (g >= 0) {
        int b = row / NA;
        float pa = __int_as_float(pos_align_i[b * M + g]);
        float po = __int_as_float(pos_ov_i[b * M + g]);
        float norm = am_val[row] * po / (pa + EPSF);
        int lbl = gt_labels[b * M + g]; if (lbl < 0) lbl = 0;
        int off = lbl - c0;
        if (off >= 0 && off < 4) ((float*)&v)[off] = norm;
    }
    reinterpret_cast<float4*>(out_scores)[q] = v;
}

// ---------------------------------------------------------------- launch

extern "C" void kernel_launch(void* const* d_in, const int* in_sizes, int n_in,
                              void* d_out, int out_size, void* d_ws, size_t ws_size,
                              hipStream_t stream) {
    const float* pd_scores  = (const float*)d_in[0];   // (B, NA, NC)
    const float* pd_circles = (const float*)d_in[1];   // (B, NA, 3)
    const float* anc        = (const float*)d_in[2];   // (NA, 2)
    const int*   gt_labels  = (const int*)  d_in[3];   // (B, M, 1)
    const float* gt_circles = (const float*)d_in[4];   // (B, M, 3)
    const float* mask_gt    = (const float*)d_in[5];   // (B, M, 1)

    // workspace layout
    char* w = (char*)d_ws;
    int*   topk        = (int*)w;   w += (size_t)B * M * KK * sizeof(int);
    int*   fg_count    = (int*)w;   w += (size_t)B * NA * sizeof(int);
    int*   sel_m       = (int*)w;   w += (size_t)B * NA * sizeof(int);
    int*   assigned    = (int*)w;   w += (size_t)B * NA * sizeof(int);
    float* am_val      = (float*)w; w += (size_t)B * NA * sizeof(float);
    int*   pos_align_i = (int*)w;   w += (size_t)B * M * sizeof(int);
    int*   pos_ov_i    = (int*)w;   w += (size_t)B * M * sizeof(int);

    // output layout (concat in return order, float32)
    float* out        = (float*)d_out;
    float* out_labels = out;                              // B*NA
    float* out_circ   = out_labels + (size_t)B * NA;      // B*NA*3
    float* out_scores = out_circ + (size_t)B * NA * 3;    // B*NA*NC
    float* out_fg     = out_scores + (size_t)B * NA * NC; // B*NA
    float* out_gtidx  = out_fg + (size_t)B * NA;          // B*NA

    const int T = 256;
    int gBA = (B * NA + T - 1) / T;

    k_init<<<gBA, T, 0, stream>>>(fg_count, sel_m, pos_align_i, pos_ov_i);

    k_topk<<<B * M, K1_THREADS, 0, stream>>>(pd_scores, pd_circles, anc,
                                             gt_labels, gt_circles, mask_gt, topk);

    k_scatter<<<(B * M * KK + T - 1) / T, T, 0, stream>>>(topk, fg_count, sel_m);

    k_resolve<<<gBA, T, 0, stream>>>(pd_circles, anc, gt_labels, gt_circles, mask_gt,
                                     fg_count, sel_m, assigned,
                                     out_labels, out_circ, out_fg, out_gtidx);

    k_posmax<<<gBA, T, 0, stream>>>(pd_scores, pd_circles, anc, gt_labels, gt_circles,
                                    mask_gt, assigned, am_val, pos_align_i, pos_ov_i);

    int nq = (B * NA * NC) / 4;
    k_scores<<<(nq + T - 1) / T, T, 0, stream>>>(assigned, am_val, pos_align_i, pos_ov_i,
                                                 gt_labels, out_scores);
}